// Round 5
// baseline (448.018 us; speedup 1.0000x reference)
//
#include <hip/hip_runtime.h>
#include <math.h>
#include <type_traits>

// ---------------------------------------------------------------------------
// CapsNet forward, fully fused routing (block = sample), pred never built:
//   s  = W_o . y  + bias_o * sum(c)     with y = sum_i c_i h[:,i]
//   db = u . h    + v.bias_o            with u = v . W_o
// Round-5: coalesced W access. S-phase reads a pre-transposed WT[o][c][d]
// (lane-linear 1KB per load instr); U-phase re-laned so the original
// row-major W is also lane-linear. float4 accumulators per lane, shorter
// butterflies, VGPR budget 128 via waves_per_eu(4,4).
// ---------------------------------------------------------------------------

__global__ __launch_bounds__(256) void conv_squash_kernel(
    const float* __restrict__ x,   // [128,64,8,8]
    const float* __restrict__ Wb,  // [64,64,3,3]
    const float* __restrict__ bb,  // [64]
    float* __restrict__ h)         // [128,64,64]
{
    __shared__ float xs[6400];
    __shared__ float hs[4096];
    __shared__ float scl[64];
    const int b = blockIdx.x;
    const int t = threadIdx.x;

    for (int idx = t; idx < 6400; idx += 256) xs[idx] = 0.f;
    __syncthreads();
    #pragma unroll
    for (int k = 0; k < 4; ++k) {
        int idx4 = t + k * 256;
        float4 v = *(const float4*)&x[(size_t)b * 4096 + idx4 * 4];
        int e0 = idx4 * 4;
        int c  = e0 >> 6;
        int hw = e0 & 63;
        int r = hw >> 3, cc = hw & 7;
        float* xp = &xs[c * 100 + (r + 1) * 10 + (cc + 1)];
        xp[0] = v.x; xp[1] = v.y; xp[2] = v.z; xp[3] = v.w;
    }
    __syncthreads();

    const int oc = t >> 2;
    const int hg = t & 3;
    float acc[16];
    #pragma unroll
    for (int k = 0; k < 16; ++k) acc[k] = 0.f;

    const float* wp = Wb + (size_t)oc * 64 * 9;
    for (int ic = 0; ic < 64; ++ic) {
        float w[9];
        #pragma unroll
        for (int j = 0; j < 9; ++j) w[j] = wp[ic * 9 + j];
        const float* xr = &xs[ic * 100];
        #pragma unroll
        for (int k = 0; k < 16; ++k) {
            int hw = hg * 16 + k;
            int r = hw >> 3, cc = hw & 7;
            int p0 = r * 10 + cc;
            float a = acc[k];
            a = fmaf(w[0], xr[p0],      a);
            a = fmaf(w[1], xr[p0 + 1],  a);
            a = fmaf(w[2], xr[p0 + 2],  a);
            a = fmaf(w[3], xr[p0 + 10], a);
            a = fmaf(w[4], xr[p0 + 11], a);
            a = fmaf(w[5], xr[p0 + 12], a);
            a = fmaf(w[6], xr[p0 + 20], a);
            a = fmaf(w[7], xr[p0 + 21], a);
            a = fmaf(w[8], xr[p0 + 22], a);
            acc[k] = a;
        }
    }
    float bias = bb[oc];
    #pragma unroll
    for (int k = 0; k < 16; ++k) {
        float v = acc[k] + bias;
        v = v > 0.f ? v : 0.f;
        hs[oc * 64 + hg * 16 + k] = v;
    }
    __syncthreads();
    if (t < 64) {
        float n2 = 0.f;
        for (int c = 0; c < 64; ++c) { float v = hs[c * 64 + t]; n2 = fmaf(v, v, n2); }
        scl[t] = (n2 / (1.f + n2)) * rsqrtf(n2 + 1e-8f);
    }
    __syncthreads();
    #pragma unroll
    for (int k = 0; k < 4; ++k) {
        int idx4 = t + k * 256;
        int e0 = idx4 * 4;
        int hw0 = e0 & 63;
        float4 o;
        o.x = hs[e0 + 0] * scl[hw0 + 0];
        o.y = hs[e0 + 1] * scl[hw0 + 1];
        o.z = hs[e0 + 2] * scl[hw0 + 2];
        o.w = hs[e0 + 3] * scl[hw0 + 3];
        *(float4*)&h[(size_t)b * 4096 + e0] = o;
    }
}

// WT[o][c][d] = W[o*64+d][c]. One block per o.
__global__ __launch_bounds__(256) void transpose_w_kernel(
    const float* __restrict__ W, float* __restrict__ WT)
{
    __shared__ float tile[64][68];
    const int o = blockIdx.x;
    const int t = threadIdx.x;
    const int Q = t & 15, R = t >> 4;
    #pragma unroll
    for (int p = 0; p < 4; ++p) {
        int d = R + 16 * p;
        float4 v = *(const float4*)&W[((size_t)o * 64 + d) * 64 + 4 * Q];
        tile[d][4 * Q + 0] = v.x; tile[d][4 * Q + 1] = v.y;
        tile[d][4 * Q + 2] = v.z; tile[d][4 * Q + 3] = v.w;
    }
    __syncthreads();
    #pragma unroll
    for (int p = 0; p < 4; ++p) {
        int c = R + 16 * p;
        float4 v;
        v.x = tile[4 * Q + 0][c];
        v.y = tile[4 * Q + 1][c];
        v.z = tile[4 * Q + 2][c];
        v.w = tile[4 * Q + 3][c];
        *(float4*)&WT[((size_t)o * 64 + c) * 64 + 4 * Q] = v;
    }
}

__global__ __launch_bounds__(1024) __attribute__((amdgpu_waves_per_eu(4, 4)))
void caps_fused(
    const float* __restrict__ h0,
    const float* __restrict__ W1, const float* __restrict__ WT1,
    const float* __restrict__ b1,
    const float* __restrict__ W2, const float* __restrict__ WT2,
    const float* __restrict__ b2,
    const float* __restrict__ b_basic, const float* __restrict__ b_cls,
    float* __restrict__ out)
{
    __shared__ float HTa[4096];
    __shared__ float HTb[4096];
    __shared__ float BL[4096];
    __shared__ float CC[4096];

    const int b    = blockIdx.x;
    const int t    = threadIdx.x;
    const int wv   = t >> 6;      // wave 0..15
    const int lane = t & 63;
    const int Q    = lane & 15;
    const int G    = lane >> 4;

    // initial transposed load: HTa[i][c] = h0[b][c][i]
    {
        float4 v = *(const float4*)&h0[(size_t)b * 4096 + t * 4];
        int c  = t >> 4;
        int i0 = (t & 15) * 4;
        HTa[(i0 + 0) * 64 + c] = v.x;
        HTa[(i0 + 1) * 64 + c] = v.y;
        HTa[(i0 + 2) * 64 + c] = v.z;
        HTa[(i0 + 3) * 64 + c] = v.w;
    }

    auto layer = [&](auto finc, const float* __restrict__ W,
                     const float* __restrict__ WT,
                     const float* __restrict__ bias,
                     const float* __restrict__ bsrc,
                     float* HT, float* HTn) {
        constexpr bool FIN = decltype(finc)::value;
        constexpr int  O   = FIN ? 10 : 64;
        constexpr int  NOO = FIN ? 1 : 4;
        float* PP = HTn;   // [16][64] overlay; HTn rows 0..15 dead at softmax

        // prefetch logits into regs
        float4 blv = make_float4(0.f, 0.f, 0.f, 0.f);
        if (FIN) {
            if (t < 160) blv = *(const float4*)&bsrc[t * 4];
        } else {
            blv = *(const float4*)&bsrc[t * 4];
        }
        // layer-invariant per-wave hoists: bias float4 (d=4Q..4Q+3) and the
        // common W/WT byte base (both use offset o*4096 + (4k+G)*64 + 4Q).
        float4 bbv[NOO];
        int    baseO[NOO];
        #pragma unroll
        for (int oo = 0; oo < NOO; ++oo) {
            int o = wv + 16 * oo;
            int om = (o < O) ? o : 0;
            bbv[oo]   = *(const float4*)&bias[om * 64 + 4 * Q];
            baseO[oo] = om * 4096 + G * 64 + 4 * Q;
        }
        __syncthreads();           // layer top: HT ready, old BL/CC dead
        if (!FIN || t < 160) *(float4*)&BL[t * 4] = blv;

        for (int it = 0; it < 3; ++it) {
            __syncthreads();   // A: BL current; HTn v-rows dead
            // -- softmax pass 1: exp + per-wave partial sums --
            float part = 0.f;
            #pragma unroll
            for (int r = 0; r < 4; ++r) {
                int o = 4 * wv + r;
                if (o < O) {
                    float e = expf(BL[o * 64 + lane]);
                    CC[o * 64 + lane] = e;
                    part += e;
                }
            }
            PP[wv * 64 + lane] = part;
            __syncthreads();   // B
            {
                float den = 0.f;
                #pragma unroll
                for (int w2 = 0; w2 < 16; ++w2) den += PP[w2 * 64 + lane];
                float rden = 1.f / den;
                #pragma unroll
                for (int r = 0; r < 4; ++r) {
                    int o = 4 * wv + r;
                    if (o < O) CC[o * 64 + lane] *= rden;
                }
            }
            __syncthreads();   // C: c complete; HT stable from here on

            if (wv < O) {
                // -- Y: y[o,c] = sum_i c[o,i] h[c,i] --
                float yy[NOO][4];
                float sc[NOO];
                #pragma unroll
                for (int a = 0; a < NOO; ++a) {
                    sc[a] = 0.f;
                    yy[a][0] = 0.f; yy[a][1] = 0.f; yy[a][2] = 0.f; yy[a][3] = 0.f;
                }
                #pragma unroll
                for (int j = 0; j < 4; ++j) {
                    float4 h4[4];
                    #pragma unroll
                    for (int r = 0; r < 4; ++r)
                        h4[r] = *(float4*)&HT[(G * 16 + 4 * j + r) * 64 + 4 * Q];
                    #pragma unroll
                    for (int oo = 0; oo < NOO; ++oo) {
                        int o = wv + 16 * oo;
                        float4 c4 = *(const float4*)&CC[o * 64 + G * 16 + 4 * j];
                        yy[oo][0] = fmaf(c4.x, h4[0].x, yy[oo][0]);
                        yy[oo][1] = fmaf(c4.x, h4[0].y, yy[oo][1]);
                        yy[oo][2] = fmaf(c4.x, h4[0].z, yy[oo][2]);
                        yy[oo][3] = fmaf(c4.x, h4[0].w, yy[oo][3]);
                        yy[oo][0] = fmaf(c4.y, h4[1].x, yy[oo][0]);
                        yy[oo][1] = fmaf(c4.y, h4[1].y, yy[oo][1]);
                        yy[oo][2] = fmaf(c4.y, h4[1].z, yy[oo][2]);
                        yy[oo][3] = fmaf(c4.y, h4[1].w, yy[oo][3]);
                        yy[oo][0] = fmaf(c4.z, h4[2].x, yy[oo][0]);
                        yy[oo][1] = fmaf(c4.z, h4[2].y, yy[oo][1]);
                        yy[oo][2] = fmaf(c4.z, h4[2].z, yy[oo][2]);
                        yy[oo][3] = fmaf(c4.z, h4[2].w, yy[oo][3]);
                        yy[oo][0] = fmaf(c4.w, h4[3].x, yy[oo][0]);
                        yy[oo][1] = fmaf(c4.w, h4[3].y, yy[oo][1]);
                        yy[oo][2] = fmaf(c4.w, h4[3].z, yy[oo][2]);
                        yy[oo][3] = fmaf(c4.w, h4[3].w, yy[oo][3]);
                        sc[oo] += (c4.x + c4.y) + (c4.z + c4.w);
                    }
                }
                #pragma unroll
                for (int m = 16; m <= 32; m <<= 1) {
                    #pragma unroll
                    for (int oo = 0; oo < NOO; ++oo) {
                        yy[oo][0] += __shfl_xor(yy[oo][0], m, 64);
                        yy[oo][1] += __shfl_xor(yy[oo][1], m, 64);
                        yy[oo][2] += __shfl_xor(yy[oo][2], m, 64);
                        yy[oo][3] += __shfl_xor(yy[oo][3], m, 64);
                        sc[oo]    += __shfl_xor(sc[oo],    m, 64);
                    }
                }
                if (G == 0) {
                    #pragma unroll
                    for (int oo = 0; oo < NOO; ++oo) {
                        int o = wv + 16 * oo;
                        float4 w4;
                        w4.x = yy[oo][0]; w4.y = yy[oo][1];
                        w4.z = yy[oo][2]; w4.w = yy[oo][3];
                        *(float4*)&CC[o * 64 + 4 * Q] = w4;   // y row
                    }
                }

                // -- S: s[o, d=4Q..4Q+3] = sum_c WT[o][c][d] y[o,c] --
                // lane-linear: per (k,oo) one fully-coalesced 1KB wave load.
                float4 s4[NOO];
                #pragma unroll
                for (int oo = 0; oo < NOO; ++oo)
                    s4[oo] = make_float4(0.f, 0.f, 0.f, 0.f);
                #pragma unroll 4
                for (int k = 0; k < 16; ++k) {
                    #pragma unroll
                    for (int oo = 0; oo < NOO; ++oo) {
                        int o = wv + 16 * oo;
                        float4 w4 = *(const float4*)&WT[baseO[oo] + (k << 8)];
                        float yv  = CC[o * 64 + 4 * k + G];   // broadcast
                        s4[oo].x = fmaf(w4.x, yv, s4[oo].x);
                        s4[oo].y = fmaf(w4.y, yv, s4[oo].y);
                        s4[oo].z = fmaf(w4.z, yv, s4[oo].z);
                        s4[oo].w = fmaf(w4.w, yv, s4[oo].w);
                    }
                }
                // reduce the c-split over G (lanes Q, Q+16, Q+32, Q+48)
                #pragma unroll
                for (int m = 16; m <= 32; m <<= 1) {
                    #pragma unroll
                    for (int oo = 0; oo < NOO; ++oo) {
                        s4[oo].x += __shfl_xor(s4[oo].x, m, 64);
                        s4[oo].y += __shfl_xor(s4[oo].y, m, 64);
                        s4[oo].z += __shfl_xor(s4[oo].z, m, 64);
                        s4[oo].w += __shfl_xor(s4[oo].w, m, 64);
                    }
                }
                float n2[NOO], sb[NOO], vd4[NOO];
                #pragma unroll
                for (int oo = 0; oo < NOO; ++oo) {
                    s4[oo].x = fmaf(bbv[oo].x, sc[oo], s4[oo].x);
                    s4[oo].y = fmaf(bbv[oo].y, sc[oo], s4[oo].y);
                    s4[oo].z = fmaf(bbv[oo].z, sc[oo], s4[oo].z);
                    s4[oo].w = fmaf(bbv[oo].w, sc[oo], s4[oo].w);
                    n2[oo] = s4[oo].x * s4[oo].x + s4[oo].y * s4[oo].y
                           + s4[oo].z * s4[oo].z + s4[oo].w * s4[oo].w;
                    sb[oo] = s4[oo].x * bbv[oo].x + s4[oo].y * bbv[oo].y
                           + s4[oo].z * bbv[oo].z + s4[oo].w * bbv[oo].w;
                }
                // fused butterfly over the 16 Q-slots (4 levels)
                #pragma unroll
                for (int m = 1; m <= 8; m <<= 1) {
                    #pragma unroll
                    for (int oo = 0; oo < NOO; ++oo) {
                        n2[oo] += __shfl_xor(n2[oo], m, 64);
                        sb[oo] += __shfl_xor(sb[oo], m, 64);
                    }
                }
                #pragma unroll
                for (int oo = 0; oo < NOO; ++oo) {
                    int o = wv + 16 * oo;
                    float scale = (n2[oo] / (1.f + n2[oo])) * rsqrtf(n2[oo] + 1e-8f);
                    float4 v4;
                    v4.x = s4[oo].x * scale; v4.y = s4[oo].y * scale;
                    v4.z = s4[oo].z * scale; v4.w = s4[oo].w * scale;
                    vd4[oo] = sb[oo] * scale;        // = v . bias_o
                    if (G == 0) {
                        *(float4*)&HTn[o * 64 + 4 * Q] = v4;
                        if (FIN && it == 2)
                            *(float4*)&out[(size_t)b * 640 + o * 64 + 4 * Q] = v4;
                    }
                }

                if (it < 2) {
                    // -- U: u[o, c=4Q..4Q+3] = sum_d v[o,d] W[o*64+d][c] --
                    // original row-major W is lane-linear in this laning.
                    float4 u4[NOO];
                    #pragma unroll
                    for (int oo = 0; oo < NOO; ++oo)
                        u4[oo] = make_float4(0.f, 0.f, 0.f, 0.f);
                    #pragma unroll 4
                    for (int k = 0; k < 16; ++k) {
                        #pragma unroll
                        for (int oo = 0; oo < NOO; ++oo) {
                            int o = wv + 16 * oo;
                            float4 w4 = *(const float4*)&W[baseO[oo] + (k << 8)];
                            float vv  = HTn[o * 64 + 4 * k + G];   // broadcast
                            u4[oo].x = fmaf(vv, w4.x, u4[oo].x);
                            u4[oo].y = fmaf(vv, w4.y, u4[oo].y);
                            u4[oo].z = fmaf(vv, w4.z, u4[oo].z);
                            u4[oo].w = fmaf(vv, w4.w, u4[oo].w);
                        }
                    }
                    #pragma unroll
                    for (int m = 16; m <= 32; m <<= 1) {
                        #pragma unroll
                        for (int oo = 0; oo < NOO; ++oo) {
                            u4[oo].x += __shfl_xor(u4[oo].x, m, 64);
                            u4[oo].y += __shfl_xor(u4[oo].y, m, 64);
                            u4[oo].z += __shfl_xor(u4[oo].z, m, 64);
                            u4[oo].w += __shfl_xor(u4[oo].w, m, 64);
                        }
                    }
                    if (G == 0) {
                        #pragma unroll
                        for (int oo = 0; oo < NOO; ++oo) {
                            int o = wv + 16 * oo;
                            *(float4*)&CC[o * 64 + 4 * Q] = u4[oo];   // u row
                        }
                    }
                    // -- DB: db[o,i=lane] = sum_c u[o,c] h[c,i] --
                    float a4[NOO];
                    #pragma unroll
                    for (int oo = 0; oo < NOO; ++oo) a4[oo] = 0.f;
                    #pragma unroll 4
                    for (int k = 0; k < 16; ++k) {
                        int cq = k ^ Q;
                        float4 hh = *(float4*)&HT[lane * 64 + 4 * cq];  // o-invariant
                        #pragma unroll
                        for (int oo = 0; oo < NOO; ++oo) {
                            int o = wv + 16 * oo;
                            float4 uu = *(float4*)&CC[o * 64 + 4 * cq];
                            a4[oo] = fmaf(uu.x, hh.x, a4[oo]);
                            a4[oo] = fmaf(uu.y, hh.y, a4[oo]);
                            a4[oo] = fmaf(uu.z, hh.z, a4[oo]);
                            a4[oo] = fmaf(uu.w, hh.w, a4[oo]);
                        }
                    }
                    #pragma unroll
                    for (int oo = 0; oo < NOO; ++oo) {
                        int o = wv + 16 * oo;
                        BL[o * 64 + lane] += a4[oo] + vd4[oo];
                    }
                }
            }
        }
    };

    layer(std::integral_constant<bool, false>{}, W1, WT1, b1,
          b_basic + (((size_t)0 * 128 + b) << 12), HTa, HTb);
    layer(std::integral_constant<bool, false>{}, W1, WT1, b1,
          b_basic + (((size_t)1 * 128 + b) << 12), HTb, HTa);
    layer(std::integral_constant<bool, false>{}, W1, WT1, b1,
          b_basic + (((size_t)2 * 128 + b) << 12), HTa, HTb);
    layer(std::integral_constant<bool, true>{}, W2, WT2, b2,
          b_cls + (size_t)b * 640, HTb, HTa);
}

extern "C" void kernel_launch(void* const* d_in, const int* in_sizes, int n_in,
                              void* d_out, int out_size, void* d_ws, size_t ws_size,
                              hipStream_t stream) {
    const float* x       = (const float*)d_in[0];
    const float* Wb      = (const float*)d_in[1];
    const float* bb      = (const float*)d_in[2];
    const float* W1      = (const float*)d_in[3];
    const float* b1      = (const float*)d_in[4];
    const float* W2      = (const float*)d_in[5];
    const float* b2      = (const float*)d_in[6];
    const float* b_basic = (const float*)d_in[7];
    const float* b_cls   = (const float*)d_in[8];
    float* out = (float*)d_out;

    float* h0  = (float*)d_ws;          // [128,64,64]   2 MB
    float* WT1 = h0  + 128 * 4096;      // [64,64,64]    1 MB
    float* WT2 = WT1 + 64 * 4096;       // [10,64,64]    160 KB

    transpose_w_kernel<<<64, 256, 0, stream>>>(W1, WT1);
    transpose_w_kernel<<<10, 256, 0, stream>>>(W2, WT2);
    conv_squash_kernel<<<128, 256, 0, stream>>>(x, Wb, bb, h0);
    caps_fused<<<128, 1024, 0, stream>>>(h0, W1, WT1, b1, W2, WT2, b2,
                                         b_basic, b_cls, out);
}

// Round 6
// 280.004 us; speedup vs baseline: 1.6000x; 1.6000x over previous
//
#include <hip/hip_runtime.h>
#include <math.h>
#include <type_traits>

// ---------------------------------------------------------------------------
// CapsNet forward, fully fused routing (block = sample), pred never built:
//   s  = W_o . y  + bias_o * sum(c)     with y = sum_i c_i h[:,i]
//   db = u . h    + v.bias_o            with u = v . W_o
// Round-6: wave-owns-o partition. Each of 16 waves owns 4 consecutive o's
// end-to-end; only cross-wave dataflow is the softmax denominator ->
// 1 block barrier/iter (+1/layer). All phase hand-offs are intra-wave LDS
// rows. Coalesced W (WT for S, W for U), HC[c][i] copy for conflict-free DB,
// logits in registers, unroll capped so the 64-VGPR budget never spills.
// ---------------------------------------------------------------------------

__global__ __launch_bounds__(256) void conv_squash_kernel(
    const float* __restrict__ x,   // [128,64,8,8]
    const float* __restrict__ Wb,  // [64,64,3,3]
    const float* __restrict__ bb,  // [64]
    float* __restrict__ h)         // [128,64,64]
{
    __shared__ float xs[6400];
    __shared__ float hs[4096];
    __shared__ float scl[64];
    const int b = blockIdx.x;
    const int t = threadIdx.x;

    for (int idx = t; idx < 6400; idx += 256) xs[idx] = 0.f;
    __syncthreads();
    #pragma unroll
    for (int k = 0; k < 4; ++k) {
        int idx4 = t + k * 256;
        float4 v = *(const float4*)&x[(size_t)b * 4096 + idx4 * 4];
        int e0 = idx4 * 4;
        int c  = e0 >> 6;
        int hw = e0 & 63;
        int r = hw >> 3, cc = hw & 7;
        float* xp = &xs[c * 100 + (r + 1) * 10 + (cc + 1)];
        xp[0] = v.x; xp[1] = v.y; xp[2] = v.z; xp[3] = v.w;
    }
    __syncthreads();

    const int oc = t >> 2;
    const int hg = t & 3;
    float acc[16];
    #pragma unroll
    for (int k = 0; k < 16; ++k) acc[k] = 0.f;

    const float* wp = Wb + (size_t)oc * 64 * 9;
    for (int ic = 0; ic < 64; ++ic) {
        float w[9];
        #pragma unroll
        for (int j = 0; j < 9; ++j) w[j] = wp[ic * 9 + j];
        const float* xr = &xs[ic * 100];
        #pragma unroll
        for (int k = 0; k < 16; ++k) {
            int hw = hg * 16 + k;
            int r = hw >> 3, cc = hw & 7;
            int p0 = r * 10 + cc;
            float a = acc[k];
            a = fmaf(w[0], xr[p0],      a);
            a = fmaf(w[1], xr[p0 + 1],  a);
            a = fmaf(w[2], xr[p0 + 2],  a);
            a = fmaf(w[3], xr[p0 + 10], a);
            a = fmaf(w[4], xr[p0 + 11], a);
            a = fmaf(w[5], xr[p0 + 12], a);
            a = fmaf(w[6], xr[p0 + 20], a);
            a = fmaf(w[7], xr[p0 + 21], a);
            a = fmaf(w[8], xr[p0 + 22], a);
            acc[k] = a;
        }
    }
    float bias = bb[oc];
    #pragma unroll
    for (int k = 0; k < 16; ++k) {
        float v = acc[k] + bias;
        v = v > 0.f ? v : 0.f;
        hs[oc * 64 + hg * 16 + k] = v;
    }
    __syncthreads();
    if (t < 64) {
        float n2 = 0.f;
        for (int c = 0; c < 64; ++c) { float v = hs[c * 64 + t]; n2 = fmaf(v, v, n2); }
        scl[t] = (n2 / (1.f + n2)) * rsqrtf(n2 + 1e-8f);
    }
    __syncthreads();
    #pragma unroll
    for (int k = 0; k < 4; ++k) {
        int idx4 = t + k * 256;
        int e0 = idx4 * 4;
        int hw0 = e0 & 63;
        float4 o;
        o.x = hs[e0 + 0] * scl[hw0 + 0];
        o.y = hs[e0 + 1] * scl[hw0 + 1];
        o.z = hs[e0 + 2] * scl[hw0 + 2];
        o.w = hs[e0 + 3] * scl[hw0 + 3];
        *(float4*)&h[(size_t)b * 4096 + e0] = o;
    }
}

// WT[o][c][d] = W[o*64+d][c]. One block per o.
__global__ __launch_bounds__(256) void transpose_w_kernel(
    const float* __restrict__ W, float* __restrict__ WT)
{
    __shared__ float tile[64][68];
    const int o = blockIdx.x;
    const int t = threadIdx.x;
    const int Q = t & 15, R = t >> 4;
    #pragma unroll
    for (int p = 0; p < 4; ++p) {
        int d = R + 16 * p;
        float4 v = *(const float4*)&W[((size_t)o * 64 + d) * 64 + 4 * Q];
        tile[d][4 * Q + 0] = v.x; tile[d][4 * Q + 1] = v.y;
        tile[d][4 * Q + 2] = v.z; tile[d][4 * Q + 3] = v.w;
    }
    __syncthreads();
    #pragma unroll
    for (int p = 0; p < 4; ++p) {
        int c = R + 16 * p;
        float4 v;
        v.x = tile[4 * Q + 0][c];
        v.y = tile[4 * Q + 1][c];
        v.z = tile[4 * Q + 2][c];
        v.w = tile[4 * Q + 3][c];
        *(float4*)&WT[((size_t)o * 64 + c) * 64 + 4 * Q] = v;
    }
}

__global__ __launch_bounds__(1024) void caps_fused(
    const float* __restrict__ h0,
    const float* __restrict__ W1, const float* __restrict__ WT1,
    const float* __restrict__ b1,
    const float* __restrict__ W2, const float* __restrict__ WT2,
    const float* __restrict__ b2,
    const float* __restrict__ b_basic, const float* __restrict__ b_cls,
    float* __restrict__ out)
{
    __shared__ float HT[4096];       // h as [i][c], stride 64
    __shared__ float HC[64 * 68];    // h as [c][i], stride 68 (bank-spread)
    __shared__ float CC[4096];       // per-o comm rows (c -> y -> v -> u -> db)
    __shared__ float PPd[2][1024];   // softmax partials, double-buffered

    const int b    = blockIdx.x;
    const int t    = threadIdx.x;
    const int wv   = t >> 6;      // wave 0..15
    const int lane = t & 63;
    const int Q    = lane & 15;   // d/c quad index
    const int G    = lane >> 4;   // k-split group

    // build both h layouts from h0[b][c][i]
    {
        float4 v = *(const float4*)&h0[(size_t)b * 4096 + t * 4];
        int c  = t >> 4;
        int i0 = (t & 15) * 4;
        *(float4*)&HC[c * 68 + i0] = v;
        HT[(i0 + 0) * 64 + c] = v.x;
        HT[(i0 + 1) * 64 + c] = v.y;
        HT[(i0 + 2) * 64 + c] = v.z;
        HT[(i0 + 3) * 64 + c] = v.w;
    }

    auto layer = [&](auto finc, const float* __restrict__ W,
                     const float* __restrict__ WT,
                     const float* __restrict__ bias,
                     const float* __restrict__ bsrc) {
        constexpr bool FIN = decltype(finc)::value;
        constexpr int  NOO = FIN ? 1 : 4;
        const bool act = !FIN || wv < 10;

        float bl[NOO];    // routing logits BL[o][lane], in registers
        if (act) {
            #pragma unroll
            for (int r = 0; r < NOO; ++r)
                bl[r] = bsrc[(FIN ? wv : 4 * wv + r) * 64 + lane];
        }
        float4 vs[NOO];   // final-iteration v carry (non-FIN)

        for (int it = 0; it < 3; ++it) {
            // ---- softmax over o: per-wave partials, ONE block barrier ----
            float cc[NOO], sc[NOO];
            float part = 0.f;
            if (act) {
                #pragma unroll
                for (int r = 0; r < NOO; ++r) { cc[r] = expf(bl[r]); part += cc[r]; }
            }
            PPd[it & 1][t] = part;
            __syncthreads();
            float den = 0.f;
            #pragma unroll
            for (int w2 = 0; w2 < 16; ++w2) den += PPd[it & 1][w2 * 64 + lane];
            float rden = 1.f / den;
            if (act) {
                #pragma unroll
                for (int r = 0; r < NOO; ++r) {
                    int o = FIN ? wv : 4 * wv + r;
                    float cv = cc[r] * rden;
                    CC[o * 64 + lane] = cv;          // c row (own wave only)
                    #pragma unroll
                    for (int m = 1; m < 64; m <<= 1) cv += __shfl_xor(cv, m, 64);
                    sc[r] = cv;                      // sum_i c[o,i]
                }
            }
            __builtin_amdgcn_wave_barrier();

            if (act) {
                // ---- Y (o-inner): y[o,4Q+j] = sum_i c[o,i] h[4Q+j,i] ----
                float4 yy[NOO];
                #pragma unroll
                for (int r = 0; r < NOO; ++r) yy[r] = make_float4(0.f, 0.f, 0.f, 0.f);
                #pragma unroll 2
                for (int k = 0; k < 16; ++k) {
                    int i = G * 16 + k;
                    float4 h4 = *(const float4*)&HT[i * 64 + 4 * Q];
                    #pragma unroll
                    for (int r = 0; r < NOO; ++r) {
                        int o = FIN ? wv : 4 * wv + r;
                        float cb = CC[o * 64 + i];
                        yy[r].x = fmaf(cb, h4.x, yy[r].x);
                        yy[r].y = fmaf(cb, h4.y, yy[r].y);
                        yy[r].z = fmaf(cb, h4.z, yy[r].z);
                        yy[r].w = fmaf(cb, h4.w, yy[r].w);
                    }
                }
                #pragma unroll
                for (int m = 16; m <= 32; m <<= 1) {
                    #pragma unroll
                    for (int r = 0; r < NOO; ++r) {
                        yy[r].x += __shfl_xor(yy[r].x, m, 64);
                        yy[r].y += __shfl_xor(yy[r].y, m, 64);
                        yy[r].z += __shfl_xor(yy[r].z, m, 64);
                        yy[r].w += __shfl_xor(yy[r].w, m, 64);
                    }
                }
                if (G == 0) {
                    #pragma unroll
                    for (int r = 0; r < NOO; ++r)
                        *(float4*)&CC[(FIN ? wv : 4 * wv + r) * 64 + 4 * Q] = yy[r];
                }
                __builtin_amdgcn_wave_barrier();

                // ---- S (o-inner, k-outer): s[o,4Q+j] = sum_c WT[o][c][4Q+j] y[c]
                float4 s4[NOO];
                #pragma unroll
                for (int r = 0; r < NOO; ++r) s4[r] = make_float4(0.f, 0.f, 0.f, 0.f);
                #pragma unroll 2
                for (int k = 0; k < 16; ++k) {
                    #pragma unroll
                    for (int r = 0; r < NOO; ++r) {
                        int o = FIN ? wv : 4 * wv + r;
                        float4 w4 = *(const float4*)&WT[o * 4096 + (4 * k + G) * 64 + 4 * Q];
                        float yv  = CC[o * 64 + 4 * k + G];
                        s4[r].x = fmaf(w4.x, yv, s4[r].x);
                        s4[r].y = fmaf(w4.y, yv, s4[r].y);
                        s4[r].z = fmaf(w4.z, yv, s4[r].z);
                        s4[r].w = fmaf(w4.w, yv, s4[r].w);
                    }
                }
                #pragma unroll
                for (int m = 16; m <= 32; m <<= 1) {
                    #pragma unroll
                    for (int r = 0; r < NOO; ++r) {
                        s4[r].x += __shfl_xor(s4[r].x, m, 64);
                        s4[r].y += __shfl_xor(s4[r].y, m, 64);
                        s4[r].z += __shfl_xor(s4[r].z, m, 64);
                        s4[r].w += __shfl_xor(s4[r].w, m, 64);
                    }
                }
                float vd[NOO];
                #pragma unroll
                for (int r = 0; r < NOO; ++r) {
                    int o = FIN ? wv : 4 * wv + r;
                    float4 bias4 = *(const float4*)&bias[o * 64 + 4 * Q];
                    s4[r].x = fmaf(bias4.x, sc[r], s4[r].x);
                    s4[r].y = fmaf(bias4.y, sc[r], s4[r].y);
                    s4[r].z = fmaf(bias4.z, sc[r], s4[r].z);
                    s4[r].w = fmaf(bias4.w, sc[r], s4[r].w);
                    float n2 = s4[r].x * s4[r].x + s4[r].y * s4[r].y
                             + s4[r].z * s4[r].z + s4[r].w * s4[r].w;
                    #pragma unroll
                    for (int m = 1; m <= 8; m <<= 1) n2 += __shfl_xor(n2, m, 64);
                    float scale = (n2 / (1.f + n2)) * rsqrtf(n2 + 1e-8f);
                    float4 v4;
                    v4.x = s4[r].x * scale; v4.y = s4[r].y * scale;
                    v4.z = s4[r].z * scale; v4.w = s4[r].w * scale;
                    float d = v4.x * bias4.x + v4.y * bias4.y
                            + v4.z * bias4.z + v4.w * bias4.w;
                    #pragma unroll
                    for (int m = 1; m <= 8; m <<= 1) d += __shfl_xor(d, m, 64);
                    vd[r] = d;                        // v . bias_o
                    if (it == 2) {
                        vs[r] = v4;
                        if (FIN && G == 0)
                            *(float4*)&out[(size_t)b * 640 + o * 64 + 4 * Q] = v4;
                    } else if (G == 0) {
                        *(float4*)&CC[o * 64 + 4 * Q] = v4;   // v row
                    }
                }

                if (it < 2) {
                    __builtin_amdgcn_wave_barrier();
                    // ---- U (o-inner): u[o,4Q+j] = sum_d v[o,d] W[o*64+d][4Q+j]
                    float4 u4[NOO];
                    #pragma unroll
                    for (int r = 0; r < NOO; ++r) u4[r] = make_float4(0.f, 0.f, 0.f, 0.f);
                    #pragma unroll 2
                    for (int k = 0; k < 16; ++k) {
                        #pragma unroll
                        for (int r = 0; r < NOO; ++r) {
                            int o = FIN ? wv : 4 * wv + r;
                            float4 w4 = *(const float4*)&W[o * 4096 + (4 * k + G) * 64 + 4 * Q];
                            float vv  = CC[o * 64 + 4 * k + G];
                            u4[r].x = fmaf(vv, w4.x, u4[r].x);
                            u4[r].y = fmaf(vv, w4.y, u4[r].y);
                            u4[r].z = fmaf(vv, w4.z, u4[r].z);
                            u4[r].w = fmaf(vv, w4.w, u4[r].w);
                        }
                    }
                    #pragma unroll
                    for (int m = 16; m <= 32; m <<= 1) {
                        #pragma unroll
                        for (int r = 0; r < NOO; ++r) {
                            u4[r].x += __shfl_xor(u4[r].x, m, 64);
                            u4[r].y += __shfl_xor(u4[r].y, m, 64);
                            u4[r].z += __shfl_xor(u4[r].z, m, 64);
                            u4[r].w += __shfl_xor(u4[r].w, m, 64);
                        }
                    }
                    if (G == 0) {
                        #pragma unroll
                        for (int r = 0; r < NOO; ++r)
                            *(float4*)&CC[(FIN ? wv : 4 * wv + r) * 64 + 4 * Q] = u4[r];
                    }
                    __builtin_amdgcn_wave_barrier();

                    // ---- DB (o-inner): db[o,4Q+j] = sum_c u[o,c] h[c,4Q+j]
                    float4 d4[NOO];
                    #pragma unroll
                    for (int r = 0; r < NOO; ++r) d4[r] = make_float4(0.f, 0.f, 0.f, 0.f);
                    #pragma unroll 2
                    for (int k = 0; k < 16; ++k) {
                        int c = G * 16 + k;
                        float4 hc4 = *(const float4*)&HC[c * 68 + 4 * Q];
                        #pragma unroll
                        for (int r = 0; r < NOO; ++r) {
                            int o = FIN ? wv : 4 * wv + r;
                            float ub = CC[o * 64 + c];
                            d4[r].x = fmaf(ub, hc4.x, d4[r].x);
                            d4[r].y = fmaf(ub, hc4.y, d4[r].y);
                            d4[r].z = fmaf(ub, hc4.z, d4[r].z);
                            d4[r].w = fmaf(ub, hc4.w, d4[r].w);
                        }
                    }
                    #pragma unroll
                    for (int m = 16; m <= 32; m <<= 1) {
                        #pragma unroll
                        for (int r = 0; r < NOO; ++r) {
                            d4[r].x += __shfl_xor(d4[r].x, m, 64);
                            d4[r].y += __shfl_xor(d4[r].y, m, 64);
                            d4[r].z += __shfl_xor(d4[r].z, m, 64);
                            d4[r].w += __shfl_xor(d4[r].w, m, 64);
                        }
                    }
                    if (G == 0) {
                        #pragma unroll
                        for (int r = 0; r < NOO; ++r)
                            *(float4*)&CC[(FIN ? wv : 4 * wv + r) * 64 + 4 * Q] = d4[r];
                    }
                    __builtin_amdgcn_wave_barrier();
                    #pragma unroll
                    for (int r = 0; r < NOO; ++r)
                        bl[r] += CC[(FIN ? wv : 4 * wv + r) * 64 + lane] + vd[r];
                }
            }
        }
        // ---- layer end: publish v as next layer's h (both layouts) ----
        __syncthreads();
        if (!FIN && act && G == 0) {
            #pragma unroll
            for (int r = 0; r < NOO; ++r) {
                int o = 4 * wv + r;
                *(float4*)&HT[o * 64 + 4 * Q] = vs[r];    // HT[i=o][c=d]
                HC[(4 * Q + 0) * 68 + o] = vs[r].x;       // HC[c=d][i=o]
                HC[(4 * Q + 1) * 68 + o] = vs[r].y;
                HC[(4 * Q + 2) * 68 + o] = vs[r].z;
                HC[(4 * Q + 3) * 68 + o] = vs[r].w;
            }
        }
        // visibility for next layer is covered by its first __syncthreads
    };

    layer(std::integral_constant<bool, false>{}, W1, WT1, b1,
          b_basic + (((size_t)0 * 128 + b) << 12));
    layer(std::integral_constant<bool, false>{}, W1, WT1, b1,
          b_basic + (((size_t)1 * 128 + b) << 12));
    layer(std::integral_constant<bool, false>{}, W1, WT1, b1,
          b_basic + (((size_t)2 * 128 + b) << 12));
    layer(std::integral_constant<bool, true>{}, W2, WT2, b2,
          b_cls + (size_t)b * 640);
}

extern "C" void kernel_launch(void* const* d_in, const int* in_sizes, int n_in,
                              void* d_out, int out_size, void* d_ws, size_t ws_size,
                              hipStream_t stream) {
    const float* x       = (const float*)d_in[0];
    const float* Wb      = (const float*)d_in[1];
    const float* bb      = (const float*)d_in[2];
    const float* W1      = (const float*)d_in[3];
    const float* b1      = (const float*)d_in[4];
    const float* W2      = (const float*)d_in[5];
    const float* b2      = (const float*)d_in[6];
    const float* b_basic = (const float*)d_in[7];
    const float* b_cls   = (const float*)d_in[8];
    float* out = (float*)d_out;

    float* h0  = (float*)d_ws;          // [128,64,64]   2 MB
    float* WT1 = h0  + 128 * 4096;      // [64,64,64]    1 MB
    float* WT2 = WT1 + 64 * 4096;       // [10,64,64]    160 KB

    transpose_w_kernel<<<64, 256, 0, stream>>>(W1, WT1);
    transpose_w_kernel<<<10, 256, 0, stream>>>(W2, WT2);
    conv_squash_kernel<<<128, 256, 0, stream>>>(x, Wb, bb, h0);
    caps_fused<<<128, 1024, 0, stream>>>(h0, W1, WT1, b1, W2, WT2, b2,
                                         b_basic, b_cls, out);
}

// Round 7
// 234.790 us; speedup vs baseline: 1.9082x; 1.1926x over previous
//
#include <hip/hip_runtime.h>
#include <math.h>
#include <type_traits>

// ---------------------------------------------------------------------------
// CapsNet forward, fully fused routing (block = sample), pred never built:
//   s  = W_o . y  + bias_o * sum(c)     with y = sum_i c_i h[:,i]
//   db = u . h    + v.bias_o            with u = v . W_o
// Round-7: force 1 block/CU (LDS pad >80KB + launch_bounds(1024,4)) so the
// VGPR cap is 128 -> no scratch spills; unroll-4 W streams (~16 loads in
// flight); layer-hoisted W base pointers (U via uniform delta) and bias;
// v persists in CC rows (no register carry), layer-end publish CC->HT/HC.
// ---------------------------------------------------------------------------

__global__ __launch_bounds__(256) void conv_squash_kernel(
    const float* __restrict__ x,   // [128,64,8,8]
    const float* __restrict__ Wb,  // [64,64,3,3]
    const float* __restrict__ bb,  // [64]
    float* __restrict__ h)         // [128,64,64]
{
    __shared__ float xs[6400];
    __shared__ float hs[4096];
    __shared__ float scl[64];
    const int b = blockIdx.x;
    const int t = threadIdx.x;

    for (int idx = t; idx < 6400; idx += 256) xs[idx] = 0.f;
    __syncthreads();
    #pragma unroll
    for (int k = 0; k < 4; ++k) {
        int idx4 = t + k * 256;
        float4 v = *(const float4*)&x[(size_t)b * 4096 + idx4 * 4];
        int e0 = idx4 * 4;
        int c  = e0 >> 6;
        int hw = e0 & 63;
        int r = hw >> 3, cc = hw & 7;
        float* xp = &xs[c * 100 + (r + 1) * 10 + (cc + 1)];
        xp[0] = v.x; xp[1] = v.y; xp[2] = v.z; xp[3] = v.w;
    }
    __syncthreads();

    const int oc = t >> 2;
    const int hg = t & 3;
    float acc[16];
    #pragma unroll
    for (int k = 0; k < 16; ++k) acc[k] = 0.f;

    const float* wp = Wb + (size_t)oc * 64 * 9;
    for (int ic = 0; ic < 64; ++ic) {
        float w[9];
        #pragma unroll
        for (int j = 0; j < 9; ++j) w[j] = wp[ic * 9 + j];
        const float* xr = &xs[ic * 100];
        #pragma unroll
        for (int k = 0; k < 16; ++k) {
            int hw = hg * 16 + k;
            int r = hw >> 3, cc = hw & 7;
            int p0 = r * 10 + cc;
            float a = acc[k];
            a = fmaf(w[0], xr[p0],      a);
            a = fmaf(w[1], xr[p0 + 1],  a);
            a = fmaf(w[2], xr[p0 + 2],  a);
            a = fmaf(w[3], xr[p0 + 10], a);
            a = fmaf(w[4], xr[p0 + 11], a);
            a = fmaf(w[5], xr[p0 + 12], a);
            a = fmaf(w[6], xr[p0 + 20], a);
            a = fmaf(w[7], xr[p0 + 21], a);
            a = fmaf(w[8], xr[p0 + 22], a);
            acc[k] = a;
        }
    }
    float bias = bb[oc];
    #pragma unroll
    for (int k = 0; k < 16; ++k) {
        float v = acc[k] + bias;
        v = v > 0.f ? v : 0.f;
        hs[oc * 64 + hg * 16 + k] = v;
    }
    __syncthreads();
    if (t < 64) {
        float n2 = 0.f;
        for (int c = 0; c < 64; ++c) { float v = hs[c * 64 + t]; n2 = fmaf(v, v, n2); }
        scl[t] = (n2 / (1.f + n2)) * rsqrtf(n2 + 1e-8f);
    }
    __syncthreads();
    #pragma unroll
    for (int k = 0; k < 4; ++k) {
        int idx4 = t + k * 256;
        int e0 = idx4 * 4;
        int hw0 = e0 & 63;
        float4 o;
        o.x = hs[e0 + 0] * scl[hw0 + 0];
        o.y = hs[e0 + 1] * scl[hw0 + 1];
        o.z = hs[e0 + 2] * scl[hw0 + 2];
        o.w = hs[e0 + 3] * scl[hw0 + 3];
        *(float4*)&h[(size_t)b * 4096 + e0] = o;
    }
}

// WT[o][c][d] = W[o*64+d][c]. One block per o.
__global__ __launch_bounds__(256) void transpose_w_kernel(
    const float* __restrict__ W, float* __restrict__ WT)
{
    __shared__ float tile[64][68];
    const int o = blockIdx.x;
    const int t = threadIdx.x;
    const int Q = t & 15, R = t >> 4;
    #pragma unroll
    for (int p = 0; p < 4; ++p) {
        int d = R + 16 * p;
        float4 v = *(const float4*)&W[((size_t)o * 64 + d) * 64 + 4 * Q];
        tile[d][4 * Q + 0] = v.x; tile[d][4 * Q + 1] = v.y;
        tile[d][4 * Q + 2] = v.z; tile[d][4 * Q + 3] = v.w;
    }
    __syncthreads();
    #pragma unroll
    for (int p = 0; p < 4; ++p) {
        int c = R + 16 * p;
        float4 v;
        v.x = tile[4 * Q + 0][c];
        v.y = tile[4 * Q + 1][c];
        v.z = tile[4 * Q + 2][c];
        v.w = tile[4 * Q + 3][c];
        *(float4*)&WT[((size_t)o * 64 + c) * 64 + 4 * Q] = v;
    }
}

__global__ __launch_bounds__(1024, 4) __attribute__((amdgpu_waves_per_eu(4, 4)))
void caps_fused(
    const float* __restrict__ h0,
    const float* __restrict__ W1, const float* __restrict__ WT1,
    const float* __restrict__ b1,
    const float* __restrict__ W2, const float* __restrict__ WT2,
    const float* __restrict__ b2,
    const float* __restrict__ b_basic, const float* __restrict__ b_cls,
    float* __restrict__ out)
{
    __shared__ float HT[4096];       // h as [i][c], stride 64          16 KB
    __shared__ float HC[64 * 68];    // h as [c][i], stride 68          17 KB
    __shared__ float CC[4096];       // per-o comm rows                 16 KB
    __shared__ float PPbig[8192];    // softmax partials [2][1024] +    32 KB
                                     // pad: total 81.4 KB -> 1 block/CU
                                     // -> compiler VGPR budget 128

    const int b    = blockIdx.x;
    const int t    = threadIdx.x;
    const int wv   = t >> 6;      // wave 0..15
    const int lane = t & 63;
    const int Q    = lane & 15;   // d/c quad index
    const int G    = lane >> 4;   // k-split group

    // build both h layouts from h0[b][c][i]
    {
        float4 v = *(const float4*)&h0[(size_t)b * 4096 + t * 4];
        int c  = t >> 4;
        int i0 = (t & 15) * 4;
        *(float4*)&HC[c * 68 + i0] = v;
        HT[(i0 + 0) * 64 + c] = v.x;
        HT[(i0 + 1) * 64 + c] = v.y;
        HT[(i0 + 2) * 64 + c] = v.z;
        HT[(i0 + 3) * 64 + c] = v.w;
    }

    auto layer = [&](auto finc, const float* __restrict__ W,
                     const float* __restrict__ WT,
                     const float* __restrict__ bias,
                     const float* __restrict__ bsrc) {
        constexpr bool FIN = decltype(finc)::value;
        constexpr int  NOO = FIN ? 1 : 4;
        const bool act = !FIN || wv < 10;

        float bl[NOO];                // routing logits BL[o][lane=i], in regs
        const float* pS[NOO];         // WT base: lane-linear S-phase stream
        float4 bias4r[NOO];
        const ptrdiff_t dWU = W - WT; // uniform delta: U-phase stream = pS+dWU
        if (act) {
            #pragma unroll
            for (int r = 0; r < NOO; ++r) {
                int o = FIN ? wv : 4 * wv + r;
                bl[r] = bsrc[o * 64 + lane];
                pS[r] = WT + o * 4096 + G * 64 + 4 * Q;
                bias4r[r] = *(const float4*)&bias[o * 64 + 4 * Q];
            }
        }

        for (int it = 0; it < 3; ++it) {
            // ---- softmax over o: per-wave partials, ONE block barrier ----
            float cc[NOO], sc[NOO];
            float part = 0.f;
            if (act) {
                #pragma unroll
                for (int r = 0; r < NOO; ++r) { cc[r] = expf(bl[r]); part += cc[r]; }
            }
            PPbig[(it & 1) * 1024 + t] = part;
            __syncthreads();
            float den = 0.f;
            #pragma unroll
            for (int w2 = 0; w2 < 16; ++w2)
                den += PPbig[(it & 1) * 1024 + w2 * 64 + lane];
            float rden = 1.f / den;
            if (act) {
                #pragma unroll
                for (int r = 0; r < NOO; ++r) {
                    int o = FIN ? wv : 4 * wv + r;
                    float cv = cc[r] * rden;
                    CC[o * 64 + lane] = cv;          // c row (own wave only)
                    #pragma unroll
                    for (int m = 1; m < 64; m <<= 1) cv += __shfl_xor(cv, m, 64);
                    sc[r] = cv;                      // sum_i c[o,i]
                }
            }
            __builtin_amdgcn_wave_barrier();

            if (act) {
                // ---- Y (o-inner): y[o,4Q+j] = sum_i c[o,i] h[4Q+j,i] ----
                float4 yy[NOO];
                #pragma unroll
                for (int r = 0; r < NOO; ++r) yy[r] = make_float4(0.f, 0.f, 0.f, 0.f);
                #pragma unroll 4
                for (int k = 0; k < 16; ++k) {
                    int i = G * 16 + k;
                    float4 h4 = *(const float4*)&HT[i * 64 + 4 * Q];
                    #pragma unroll
                    for (int r = 0; r < NOO; ++r) {
                        int o = FIN ? wv : 4 * wv + r;
                        float cb = CC[o * 64 + i];
                        yy[r].x = fmaf(cb, h4.x, yy[r].x);
                        yy[r].y = fmaf(cb, h4.y, yy[r].y);
                        yy[r].z = fmaf(cb, h4.z, yy[r].z);
                        yy[r].w = fmaf(cb, h4.w, yy[r].w);
                    }
                }
                #pragma unroll
                for (int m = 16; m <= 32; m <<= 1) {
                    #pragma unroll
                    for (int r = 0; r < NOO; ++r) {
                        yy[r].x += __shfl_xor(yy[r].x, m, 64);
                        yy[r].y += __shfl_xor(yy[r].y, m, 64);
                        yy[r].z += __shfl_xor(yy[r].z, m, 64);
                        yy[r].w += __shfl_xor(yy[r].w, m, 64);
                    }
                }
                if (G == 0) {
                    #pragma unroll
                    for (int r = 0; r < NOO; ++r)
                        *(float4*)&CC[(FIN ? wv : 4 * wv + r) * 64 + 4 * Q] = yy[r];
                }
                __builtin_amdgcn_wave_barrier();

                // ---- S (o-inner, k-outer): s[o,4Q+j] = sum_c WT[o][c][4Q+j] y[c]
                float4 s4[NOO];
                #pragma unroll
                for (int r = 0; r < NOO; ++r) s4[r] = make_float4(0.f, 0.f, 0.f, 0.f);
                #pragma unroll 4
                for (int k = 0; k < 16; ++k) {
                    #pragma unroll
                    for (int r = 0; r < NOO; ++r) {
                        int o = FIN ? wv : 4 * wv + r;
                        float4 w4 = *(const float4*)&pS[r][k << 8];
                        float yv  = CC[o * 64 + 4 * k + G];
                        s4[r].x = fmaf(w4.x, yv, s4[r].x);
                        s4[r].y = fmaf(w4.y, yv, s4[r].y);
                        s4[r].z = fmaf(w4.z, yv, s4[r].z);
                        s4[r].w = fmaf(w4.w, yv, s4[r].w);
                    }
                }
                #pragma unroll
                for (int m = 16; m <= 32; m <<= 1) {
                    #pragma unroll
                    for (int r = 0; r < NOO; ++r) {
                        s4[r].x += __shfl_xor(s4[r].x, m, 64);
                        s4[r].y += __shfl_xor(s4[r].y, m, 64);
                        s4[r].z += __shfl_xor(s4[r].z, m, 64);
                        s4[r].w += __shfl_xor(s4[r].w, m, 64);
                    }
                }
                float vd[NOO];
                #pragma unroll
                for (int r = 0; r < NOO; ++r) {
                    int o = FIN ? wv : 4 * wv + r;
                    s4[r].x = fmaf(bias4r[r].x, sc[r], s4[r].x);
                    s4[r].y = fmaf(bias4r[r].y, sc[r], s4[r].y);
                    s4[r].z = fmaf(bias4r[r].z, sc[r], s4[r].z);
                    s4[r].w = fmaf(bias4r[r].w, sc[r], s4[r].w);
                    float n2 = s4[r].x * s4[r].x + s4[r].y * s4[r].y
                             + s4[r].z * s4[r].z + s4[r].w * s4[r].w;
                    #pragma unroll
                    for (int m = 1; m <= 8; m <<= 1) n2 += __shfl_xor(n2, m, 64);
                    float scale = (n2 / (1.f + n2)) * rsqrtf(n2 + 1e-8f);
                    float4 v4;
                    v4.x = s4[r].x * scale; v4.y = s4[r].y * scale;
                    v4.z = s4[r].z * scale; v4.w = s4[r].w * scale;
                    if (it < 2) {
                        float d = v4.x * bias4r[r].x + v4.y * bias4r[r].y
                                + v4.z * bias4r[r].z + v4.w * bias4r[r].w;
                        #pragma unroll
                        for (int m = 1; m <= 8; m <<= 1) d += __shfl_xor(d, m, 64);
                        vd[r] = d;                    // v . bias_o
                    }
                    if (G == 0) {
                        *(float4*)&CC[o * 64 + 4 * Q] = v4;   // v row (persists)
                        if (FIN && it == 2)
                            *(float4*)&out[(size_t)b * 640 + o * 64 + 4 * Q] = v4;
                    }
                }

                if (it < 2) {
                    __builtin_amdgcn_wave_barrier();
                    // ---- U (o-inner): u[o,4Q+j] = sum_d v[o,d] W[o*64+d][4Q+j]
                    float4 u4[NOO];
                    #pragma unroll
                    for (int r = 0; r < NOO; ++r) u4[r] = make_float4(0.f, 0.f, 0.f, 0.f);
                    #pragma unroll 4
                    for (int k = 0; k < 16; ++k) {
                        #pragma unroll
                        for (int r = 0; r < NOO; ++r) {
                            int o = FIN ? wv : 4 * wv + r;
                            float4 w4 = *(const float4*)&pS[r][(k << 8) + dWU];
                            float vv  = CC[o * 64 + 4 * k + G];
                            u4[r].x = fmaf(vv, w4.x, u4[r].x);
                            u4[r].y = fmaf(vv, w4.y, u4[r].y);
                            u4[r].z = fmaf(vv, w4.z, u4[r].z);
                            u4[r].w = fmaf(vv, w4.w, u4[r].w);
                        }
                    }
                    #pragma unroll
                    for (int m = 16; m <= 32; m <<= 1) {
                        #pragma unroll
                        for (int r = 0; r < NOO; ++r) {
                            u4[r].x += __shfl_xor(u4[r].x, m, 64);
                            u4[r].y += __shfl_xor(u4[r].y, m, 64);
                            u4[r].z += __shfl_xor(u4[r].z, m, 64);
                            u4[r].w += __shfl_xor(u4[r].w, m, 64);
                        }
                    }
                    if (G == 0) {
                        #pragma unroll
                        for (int r = 0; r < NOO; ++r)
                            *(float4*)&CC[(FIN ? wv : 4 * wv + r) * 64 + 4 * Q] = u4[r];
                    }
                    __builtin_amdgcn_wave_barrier();

                    // ---- DB (o-inner): db[o,4Q+j] = sum_c u[o,c] h[c,4Q+j]
                    float4 d4[NOO];
                    #pragma unroll
                    for (int r = 0; r < NOO; ++r) d4[r] = make_float4(0.f, 0.f, 0.f, 0.f);
                    #pragma unroll 4
                    for (int k = 0; k < 16; ++k) {
                        int c = G * 16 + k;
                        float4 hc4 = *(const float4*)&HC[c * 68 + 4 * Q];
                        #pragma unroll
                        for (int r = 0; r < NOO; ++r) {
                            int o = FIN ? wv : 4 * wv + r;
                            float ub = CC[o * 64 + c];
                            d4[r].x = fmaf(ub, hc4.x, d4[r].x);
                            d4[r].y = fmaf(ub, hc4.y, d4[r].y);
                            d4[r].z = fmaf(ub, hc4.z, d4[r].z);
                            d4[r].w = fmaf(ub, hc4.w, d4[r].w);
                        }
                    }
                    #pragma unroll
                    for (int m = 16; m <= 32; m <<= 1) {
                        #pragma unroll
                        for (int r = 0; r < NOO; ++r) {
                            d4[r].x += __shfl_xor(d4[r].x, m, 64);
                            d4[r].y += __shfl_xor(d4[r].y, m, 64);
                            d4[r].z += __shfl_xor(d4[r].z, m, 64);
                            d4[r].w += __shfl_xor(d4[r].w, m, 64);
                        }
                    }
                    if (G == 0) {
                        #pragma unroll
                        for (int r = 0; r < NOO; ++r)
                            *(float4*)&CC[(FIN ? wv : 4 * wv + r) * 64 + 4 * Q] = d4[r];
                    }
                    __builtin_amdgcn_wave_barrier();
                    #pragma unroll
                    for (int r = 0; r < NOO; ++r)
                        bl[r] += CC[(FIN ? wv : 4 * wv + r) * 64 + lane] + vd[r];
                }
            }
        }
        // ---- layer end: publish v (in CC rows) as next layer's h ----
        __syncthreads();
        if (!FIN) {
            float4 vv = *(const float4*)&CC[t * 4];
            int o  = t >> 4;            // this layer's out-cap = next layer's i
            int d0 = (t & 15) * 4;
            *(float4*)&HT[t * 4] = vv;  // HT[i=o][c=d] — direct copy
            HC[(d0 + 0) * 68 + o] = vv.x;
            HC[(d0 + 1) * 68 + o] = vv.y;
            HC[(d0 + 2) * 68 + o] = vv.z;
            HC[(d0 + 3) * 68 + o] = vv.w;
        }
        // visibility for next layer covered by its first __syncthreads
    };

    layer(std::integral_constant<bool, false>{}, W1, WT1, b1,
          b_basic + (((size_t)0 * 128 + b) << 12));
    layer(std::integral_constant<bool, false>{}, W1, WT1, b1,
          b_basic + (((size_t)1 * 128 + b) << 12));
    layer(std::integral_constant<bool, false>{}, W1, WT1, b1,
          b_basic + (((size_t)2 * 128 + b) << 12));
    layer(std::integral_constant<bool, true>{}, W2, WT2, b2,
          b_cls + (size_t)b * 640);
}

extern "C" void kernel_launch(void* const* d_in, const int* in_sizes, int n_in,
                              void* d_out, int out_size, void* d_ws, size_t ws_size,
                              hipStream_t stream) {
    const float* x       = (const float*)d_in[0];
    const float* Wb      = (const float*)d_in[1];
    const float* bb      = (const float*)d_in[2];
    const float* W1      = (const float*)d_in[3];
    const float* b1      = (const float*)d_in[4];
    const float* W2      = (const float*)d_in[5];
    const float* b2      = (const float*)d_in[6];
    const float* b_basic = (const float*)d_in[7];
    const float* b_cls   = (const float*)d_in[8];
    float* out = (float*)d_out;

    float* h0  = (float*)d_ws;          // [128,64,64]   2 MB
    float* WT1 = h0  + 128 * 4096;      // [64,64,64]    1 MB
    float* WT2 = WT1 + 64 * 4096;       // [10,64,64]    160 KB

    transpose_w_kernel<<<64, 256, 0, stream>>>(W1, WT1);
    transpose_w_kernel<<<10, 256, 0, stream>>>(W2, WT2);
    conv_squash_kernel<<<128, 256, 0, stream>>>(x, Wb, bb, h0);
    caps_fused<<<128, 1024, 0, stream>>>(h0, W1, WT1, b1, W2, WT2, b2,
                                         b_basic, b_cls, out);
}